// Round 1
// baseline (5567.690 us; speedup 1.0000x reference)
//
#include <hip/hip_runtime.h>
#include <hip/hip_bf16.h>

#define F_DIM   13
#define EDGE_IN 34
#define MSG_DIM 32
#define HID     64
#define NODE_IN 45
#define N_L     20000
#define N_H     100000
#define E_CNT   800000
#define B_CNT   4

__device__ __forceinline__ float fast_tanh(float x) {
    x = fminf(10.f, fmaxf(-10.f, x));
    float e = __expf(2.f * x);
    return (e - 1.f) / (e + 1.f);
}
__device__ __forceinline__ float fast_sigmoid(float x) {
    x = fminf(30.f, fmaxf(-30.f, x));
    return 1.f / (1.f + __expf(-x));
}

// One thread per edge. Weights staged in LDS; MLPs fully unrolled.
__global__ __launch_bounds__(256) void edge_kernel(
    const float* __restrict__ z_l, const float* __restrict__ z_h,
    const int* __restrict__ src, const int* __restrict__ tgt,
    const float* __restrict__ We1, const float* __restrict__ be1,
    const float* __restrict__ We2, const float* __restrict__ be2,
    const float* __restrict__ Ww1, const float* __restrict__ bw1,
    const float* __restrict__ Ww2, const float* __restrict__ bw2,
    float* __restrict__ agg)
{
    __shared__ float sWe1[EDGE_IN * HID];
    __shared__ float sWw1[EDGE_IN * HID];
    __shared__ float sWe2[HID * MSG_DIM];
    __shared__ float sbe1[HID], sbw1[HID], sWw2[HID], sbe2[MSG_DIM];
    __shared__ float sbw2;

    for (int i = threadIdx.x; i < EDGE_IN * HID; i += 256) { sWe1[i] = We1[i]; sWw1[i] = Ww1[i]; }
    for (int i = threadIdx.x; i < HID * MSG_DIM; i += 256) sWe2[i] = We2[i];
    if (threadIdx.x < HID) {
        sbe1[threadIdx.x] = be1[threadIdx.x];
        sbw1[threadIdx.x] = bw1[threadIdx.x];
        sWw2[threadIdx.x] = Ww2[threadIdx.x];
    }
    if (threadIdx.x < MSG_DIM) sbe2[threadIdx.x] = be2[threadIdx.x];
    if (threadIdx.x == 0) sbw2 = bw2[0];
    __syncthreads();

    int gid = blockIdx.x * 256 + threadIdx.x;   // B*E = 3,200,000 = 12500*256 exactly
    int b = gid / E_CNT;
    int e = gid - b * E_CNT;
    int s = src[(size_t)b * E_CNT + e];
    int t = tgt[(size_t)b * E_CNT + e];

    const float* zs = z_l + ((size_t)b * N_L + s) * F_DIM;
    const float* zt = z_h + ((size_t)b * N_H + t) * F_DIM;

    float inp[EDGE_IN];
    #pragma unroll
    for (int i = 0; i < F_DIM; i++) inp[i] = zs[i];
    #pragma unroll
    for (int i = 0; i < F_DIM; i++) inp[F_DIM + i] = zt[i];
    float d0 = inp[0] - inp[13], d1 = inp[1] - inp[14], d2 = inp[2] - inp[15];
    inp[26] = d0; inp[27] = d1; inp[28] = d2;
    inp[29] = d0 * d0 + d1 * d1 + d2 * d2;
    float ax = inp[3], ay = inp[4], az = inp[5];
    float bx = inp[16], by = inp[17], bz = inp[18];
    float cx = ay * bz - az * by;
    float cy = az * bx - ax * bz;
    float cz = ax * by - ay * bx;
    inp[30] = cx; inp[31] = cy; inp[32] = cz;
    inp[33] = sqrtf(cx * cx + cy * cy + cz * cz);

    float hid[HID];

    // gate path: 34 -> 64 -> 1, sigmoid
    #pragma unroll
    for (int h = 0; h < HID; h++) hid[h] = sbw1[h];
    #pragma unroll
    for (int k = 0; k < EDGE_IN; k++) {
        float x = inp[k];
        #pragma unroll
        for (int h = 0; h < HID; h++) hid[h] = fmaf(x, sWw1[k * HID + h], hid[h]);
    }
    float w = sbw2;
    #pragma unroll
    for (int h = 0; h < HID; h++) w += fast_tanh(hid[h]) * sWw2[h];
    w = fast_sigmoid(w);

    // message path: 34 -> 64 -> 32
    #pragma unroll
    for (int h = 0; h < HID; h++) hid[h] = sbe1[h];
    #pragma unroll
    for (int k = 0; k < EDGE_IN; k++) {
        float x = inp[k];
        #pragma unroll
        for (int h = 0; h < HID; h++) hid[h] = fmaf(x, sWe1[k * HID + h], hid[h]);
    }
    float m[MSG_DIM];
    #pragma unroll
    for (int j = 0; j < MSG_DIM; j++) m[j] = sbe2[j];
    #pragma unroll
    for (int h = 0; h < HID; h++) {
        float th = fast_tanh(hid[h]);
        #pragma unroll
        for (int j = 0; j < MSG_DIM; j++) m[j] = fmaf(th, sWe2[h * MSG_DIM + j], m[j]);
    }

    float* dst = agg + ((size_t)b * N_H + t) * MSG_DIM;
    #pragma unroll
    for (int j = 0; j < MSG_DIM; j++) atomicAdd(dst + j, w * m[j]);
}

// One thread per high node: out = tanh([z_h, agg] @ Wn1 + bn1) @ Wn2 + bn2
__global__ __launch_bounds__(256) void node_kernel(
    const float* __restrict__ z_h, const float* __restrict__ agg,
    const float* __restrict__ Wn1, const float* __restrict__ bn1,
    const float* __restrict__ Wn2, const float* __restrict__ bn2,
    float* __restrict__ out)
{
    __shared__ float sWn1[NODE_IN * HID];
    __shared__ float sWn2[HID * F_DIM];
    __shared__ float sbn1[HID], sbn2[F_DIM];
    for (int i = threadIdx.x; i < NODE_IN * HID; i += 256) sWn1[i] = Wn1[i];
    for (int i = threadIdx.x; i < HID * F_DIM; i += 256) sWn2[i] = Wn2[i];
    if (threadIdx.x < HID) sbn1[threadIdx.x] = bn1[threadIdx.x];
    if (threadIdx.x < F_DIM) sbn2[threadIdx.x] = bn2[threadIdx.x];
    __syncthreads();

    size_t gid = (size_t)blockIdx.x * 256 + threadIdx.x;
    if (gid >= (size_t)B_CNT * N_H) return;

    float inp[NODE_IN];
    #pragma unroll
    for (int i = 0; i < F_DIM; i++) inp[i] = z_h[gid * F_DIM + i];
    #pragma unroll
    for (int i = 0; i < MSG_DIM; i++) inp[F_DIM + i] = agg[gid * MSG_DIM + i];

    float hid[HID];
    #pragma unroll
    for (int h = 0; h < HID; h++) hid[h] = sbn1[h];
    #pragma unroll
    for (int k = 0; k < NODE_IN; k++) {
        float x = inp[k];
        #pragma unroll
        for (int h = 0; h < HID; h++) hid[h] = fmaf(x, sWn1[k * HID + h], hid[h]);
    }
    float o[F_DIM];
    #pragma unroll
    for (int j = 0; j < F_DIM; j++) o[j] = sbn2[j];
    #pragma unroll
    for (int h = 0; h < HID; h++) {
        float th = fast_tanh(hid[h]);
        #pragma unroll
        for (int j = 0; j < F_DIM; j++) o[j] = fmaf(th, sWn2[h * F_DIM + j], o[j]);
    }
    #pragma unroll
    for (int j = 0; j < F_DIM; j++) out[gid * F_DIM + j] = o[j];
}

extern "C" void kernel_launch(void* const* d_in, const int* in_sizes, int n_in,
                              void* d_out, int out_size, void* d_ws, size_t ws_size,
                              hipStream_t stream)
{
    const float* z_l = (const float*)d_in[0];
    const float* z_h = (const float*)d_in[1];
    const int*   src = (const int*)d_in[2];
    const int*   tgt = (const int*)d_in[3];
    const float* We1 = (const float*)d_in[4];  const float* be1 = (const float*)d_in[5];
    const float* We2 = (const float*)d_in[6];  const float* be2 = (const float*)d_in[7];
    const float* Ww1 = (const float*)d_in[8];  const float* bw1 = (const float*)d_in[9];
    const float* Ww2 = (const float*)d_in[10]; const float* bw2 = (const float*)d_in[11];
    const float* Wn1 = (const float*)d_in[12]; const float* bn1 = (const float*)d_in[13];
    const float* Wn2 = (const float*)d_in[14]; const float* bn2 = (const float*)d_in[15];

    float* agg = (float*)d_ws;   // B*N_H*MSG_DIM fp32 = 51.2 MB
    size_t aggBytes = (size_t)B_CNT * N_H * MSG_DIM * sizeof(float);
    hipMemsetAsync(agg, 0, aggBytes, stream);

    edge_kernel<<<(B_CNT * E_CNT) / 256, 256, 0, stream>>>(
        z_l, z_h, src, tgt, We1, be1, We2, be2, Ww1, bw1, Ww2, bw2, agg);

    int nodeThreads = B_CNT * N_H;
    node_kernel<<<(nodeThreads + 255) / 256, 256, 0, stream>>>(
        z_h, agg, Wn1, bn1, Wn2, bn2, (float*)d_out);
}